// Round 14
// baseline (88.941 us; speedup 1.0000x reference)
//
#include <hip/hip_runtime.h>

// Closing = erosion(identity) ∘ dilation(sum over CIN=3), K=5, edge padding.
// v14 = v13 (balanced tasks, 32x48 tile, packed-f16, 2 barriers) + weight prep:
//  - prep kernel converts wd -> h2-splat uint32 (1200) and we -> NEGATED h2-splat
//    (400) into d_ws once per call; main kernel reads them via block-uniform
//    addresses -> s_load -> SGPR operands to v_pk ops (removes ~100 v_cvt/thread)
//  - dilation: 36r x 7 strips of 8c = 252 tasks; erosion: 32r x 8 strips of 6c = 256
//  - grid (6,8,64) = 3072 blocks; last col band overlaps idempotently
//  - LDS 17.5KB; named vars only (spill lessons v2/v7/v9/v11)

typedef _Float16 h2 __attribute__((ext_vector_type(2)));

namespace {
constexpr int HH = 256, WW = 256, CI = 3;
constexpr int XS2 = 28;            // sx row stride (h2)
constexpr int CH2 = 40 * XS2;      // per-channel h2 count (1120)
constexpr int DS2 = 28;            // sdil row stride (h2)
}

struct __align__(16) H4  { h2 a, b, c, d; };
struct __align__(8)  H2p { h2 a, b; };

__device__ __forceinline__ h2 pmax(h2 a, h2 b) { return __builtin_elementwise_max(a, b); }
__device__ __forceinline__ h2 pmin(h2 a, h2 b) { return __builtin_elementwise_min(a, b); }

__device__ __forceinline__ h2 shr1(h2 lo, h2 hi) {   // (lo.y, hi.x) — one alignbit
    unsigned a = __builtin_bit_cast(unsigned, lo);
    unsigned b = __builtin_bit_cast(unsigned, hi);
    return __builtin_bit_cast(h2, (a >> 16) | (b << 16));
}

__device__ __forceinline__ h2 splat2(float f) {      // one v_cvt_pkrtz_f16_f32
    auto p = __builtin_amdgcn_cvt_pkrtz(f, f);
    return __builtin_bit_cast(h2, p);
}

__device__ __forceinline__ h2 ldw(const unsigned* p, int i) {   // uniform -> s_load
    return __builtin_bit_cast(h2, p[i]);
}

// ---- prep: splat-convert weights into d_ws (runs every call, same work) ----
__global__ void prep_weights(const float* __restrict__ wd, const float* __restrict__ we,
                             unsigned* __restrict__ wsbuf) {
    const int i = threadIdx.x + blockIdx.x * 256;
    if (i < 1200) {
        wsbuf[i] = __builtin_bit_cast(unsigned, splat2(wd[i]));
    } else if (i < 1600) {
        wsbuf[i] = __builtin_bit_cast(unsigned, splat2(-we[i - 1200]));
    }
}

__global__ __launch_bounds__(256, 4)
void closing_v14(const float* __restrict__ x, const unsigned* __restrict__ wh,
                 float* __restrict__ out) {
    __shared__ __align__(16) h2 sx2[CI * CH2 + 8];   // 13472 B
    __shared__ __align__(16) h2 sd2[36 * DS2];       //  4032 B

    const int tid = threadIdx.x;
    const int bx = blockIdx.x, by = blockIdx.y, z = blockIdx.z;
    const int o = z & 15, b = z >> 4;
    const int i0 = by * 32;
    const int j0 = min(bx * 48, WW - 48);   // 0,48,96,144,192,208 (last overlaps)
    const float* xb = x + (size_t)b * (CI * HH * WW);

    // ---- stage x: 3ch x 40 rows x 56 cols as h2, ONE phase ----
#pragma unroll
    for (int k = 0; k < 7; ++k) {
        const int idx = tid + (k << 8);
        if (idx < 1680) {
            const int c   = idx / 560;
            const int rem = idx - c * 560;
            const int r   = rem / 14;
            const int q   = rem - r * 14;
            const int gi  = min(max(i0 - 4 + r, 0), HH - 1);
            const int gj0 = j0 - 4 + (q << 2);
            const float* rowp = xb + c * (HH * WW) + (gi << 8);
            float4 v;
            if (gj0 < 0)        { const float t = rowp[0];      v = make_float4(t, t, t, t); }
            else if (gj0 > 252) { const float t = rowp[WW - 1]; v = make_float4(t, t, t, t); }
            else                  v = *(const float4*)(rowp + gj0);
            H2p hw;
            hw.a = h2{(_Float16)v.x, (_Float16)v.y};
            hw.b = h2{(_Float16)v.z, (_Float16)v.w};
            *(H2p*)&sx2[c * CH2 + r * XS2 + (q << 1)] = hw;
        }
    }
    __syncthreads();

    // ---- dilation: 36 rows x 7 strips of 8 cols = 252 tasks (~1/thread) ----
    if (tid < 252) {
        const int r = tid / 7, s = tid - r * 7;   // dilated row r, h2 cols 4s..4s+3
        h2 acc0 = splat2(0.f), acc1 = acc0, acc2 = acc0, acc3 = acc0;
#pragma unroll
        for (int c = 0; c < CI; ++c) {
            const unsigned* wr = wh + (o * CI + c) * 25;   // uniform -> s_load (pre-splat h2)
            h2 m0 = splat2(-60000.f), m1 = m0, m2 = m0, m3 = m0;
            const int base = c * CH2 + r * XS2 + (s << 2);
#pragma unroll
            for (int r5 = 0; r5 < 5; ++r5) {
                const H4  A = *(const H4*)&sx2[base + r5 * XS2];
                const H2p B = *(const H2p*)&sx2[base + r5 * XS2 + 4];
                const h2 h0 = A.a, h1 = A.b, h2_ = A.c, h3 = A.d, h4 = B.a, h5 = B.b;
                const h2 t0 = shr1(h0, h1), t1 = shr1(h1, h2_), t2 = shr1(h2_, h3),
                         t3 = shr1(h3, h4), t4 = shr1(h4, h5);
                const h2 w0 = ldw(wr, r5*5+0), w1 = ldw(wr, r5*5+1), w2 = ldw(wr, r5*5+2),
                         w3 = ldw(wr, r5*5+3), w4 = ldw(wr, r5*5+4);
                m0 = pmax(m0, pmax(pmax(h0 + w0, t0 + w1), pmax(h1 + w2, pmax(t1 + w3, h2_ + w4))));
                m1 = pmax(m1, pmax(pmax(h1 + w0, t1 + w1), pmax(h2_ + w2, pmax(t2 + w3, h3 + w4))));
                m2 = pmax(m2, pmax(pmax(h2_ + w0, t2 + w1), pmax(h3 + w2, pmax(t3 + w3, h4 + w4))));
                m3 = pmax(m3, pmax(pmax(h3 + w0, t3 + w1), pmax(h4 + w2, pmax(t4 + w3, h5 + w4))));
            }
            acc0 = acc0 + m0; acc1 = acc1 + m1; acc2 = acc2 + m2; acc3 = acc3 + m3;
        }
        // erosion-input pad replication (fused)
        if (j0 == 0       && s == 0) acc0 = (h2)acc1.x;   // dilated cols 0,1 <- col 2
        if (j0 == WW - 48 && s == 6) acc1 = (h2)acc0.y;   // dilated cols 50,51 <- col 49
        const bool top = (by == 0), bot = (by == 7);
        if (!((top && r < 2) || (bot && r > 33))) {
            const int db = r * DS2 + (s << 2);
            if (s < 6) { const H4 p = {acc0, acc1, acc2, acc3}; *(H4*)&sd2[db] = p; }
            else       { const H2p p = {acc0, acc1};            *(H2p*)&sd2[db] = p; }
            if (top && r == 2) {
                if (s < 6) { const H4 p = {acc0, acc1, acc2, acc3};
                             *(H4*)&sd2[0 * DS2 + (s << 2)] = p;
                             *(H4*)&sd2[1 * DS2 + (s << 2)] = p; }
                else       { const H2p p = {acc0, acc1};
                             *(H2p*)&sd2[0 * DS2 + (s << 2)] = p;
                             *(H2p*)&sd2[1 * DS2 + (s << 2)] = p; }
            }
            if (bot && r == 33) {
                if (s < 6) { const H4 p = {acc0, acc1, acc2, acc3};
                             *(H4*)&sd2[34 * DS2 + (s << 2)] = p;
                             *(H4*)&sd2[35 * DS2 + (s << 2)] = p; }
                else       { const H2p p = {acc0, acc1};
                             *(H2p*)&sd2[34 * DS2 + (s << 2)] = p;
                             *(H2p*)&sd2[35 * DS2 + (s << 2)] = p; }
            }
        }
    }
    __syncthreads();

    // ---- erosion: 32 rows x 8 strips of 6 cols = exactly 256 tasks ----
    {
        const int r = tid >> 3, s = tid & 7;      // out row r, cols 6s..6s+5
        const unsigned* ew = wh + 1200 + o * 25;  // uniform -> s_load (pre-negated h2)
        const int eb = r * DS2 + 3 * s;
        h2 n0 = splat2(60000.f), n1 = n0, n2 = n0;
#pragma unroll
        for (int r5 = 0; r5 < 5; ++r5) {
            const h2 e0 = sd2[eb + r5 * DS2];
            const h2 e1 = sd2[eb + r5 * DS2 + 1];
            const h2 e2 = sd2[eb + r5 * DS2 + 2];
            const h2 e3 = sd2[eb + r5 * DS2 + 3];
            const h2 e4 = sd2[eb + r5 * DS2 + 4];
            const h2 t0 = shr1(e0, e1), t1 = shr1(e1, e2), t2 = shr1(e2, e3),
                     t3 = shr1(e3, e4);
            const h2 w0 = ldw(ew, r5*5+0), w1 = ldw(ew, r5*5+1), w2 = ldw(ew, r5*5+2),
                     w3 = ldw(ew, r5*5+3), w4 = ldw(ew, r5*5+4);
            n0 = pmin(n0, pmin(pmin(e0 + w0, t0 + w1), pmin(e1 + w2, pmin(t1 + w3, e2 + w4))));
            n1 = pmin(n1, pmin(pmin(e1 + w0, t1 + w1), pmin(e2 + w2, pmin(t2 + w3, e3 + w4))));
            n2 = pmin(n2, pmin(pmin(e2 + w0, t2 + w1), pmin(e3 + w2, pmin(t3 + w3, e4 + w4))));
        }
        float* op = out + ((size_t)z << 16) + ((size_t)(i0 + r) << 8) + j0 + 6 * s;
        *(float2*)op       = make_float2((float)n0.x, (float)n0.y);
        *(float2*)(op + 2) = make_float2((float)n1.x, (float)n1.y);
        *(float2*)(op + 4) = make_float2((float)n2.x, (float)n2.y);
    }
}

extern "C" void kernel_launch(void* const* d_in, const int* in_sizes, int n_in,
                              void* d_out, int out_size, void* d_ws, size_t ws_size,
                              hipStream_t stream) {
    const float* x  = (const float*)d_in[0];   // (4,3,256,256)
    const float* wd = (const float*)d_in[1];   // (16,3,5,5)
    const float* we = (const float*)d_in[2];   // (16,5,5)
    float* out = (float*)d_out;                // (4,16,256,256)
    unsigned* wsbuf = (unsigned*)d_ws;         // 1600 uint32 = 6.4KB

    prep_weights<<<dim3(7), dim3(256), 0, stream>>>(wd, we, wsbuf);
    dim3 grid(6, 8, 64);                       // 32x48 tiles; last col band overlaps
    closing_v14<<<grid, dim3(256), 0, stream>>>(x, wsbuf, out);
}